// Round 2
// baseline (140.569 us; speedup 1.0000x reference)
//
#include <hip/hip_runtime.h>

// Row-wise dot product: out[n] = sum_d x[n][d] * y[n][d]
// N = 16384 rows, D = 1024 cols, fp32 in / fp32 out.
//
// R1: one WAVE per row (was: one 4-wave block per row with LDS+barrier).
// Each lane loads 4 float4 from x and 4 from y (8 independent 16B loads in
// flight -> high MLP), 16 FMAs into 4 split accumulators, then a single
// 6-step wave shuffle reduction. No LDS, no __syncthreads.
// 256-thread block = 4 waves = 4 rows; grid = N/4 = 4096 blocks.

#define D 1024

__global__ __launch_bounds__(256) void rowdot_kernel(const float* __restrict__ x,
                                                     const float* __restrict__ y,
                                                     float* __restrict__ out) {
    const int wave = threadIdx.x >> 6;
    const int lane = threadIdx.x & 63;
    const int row = blockIdx.x * 4 + wave;

    const float4* __restrict__ xr = (const float4*)(x + (size_t)row * D);
    const float4* __restrict__ yr = (const float4*)(y + (size_t)row * D);

    // 4 coalesced chunks of 64 float4s each: lane l reads float4 l, l+64, l+128, l+192
    float4 a0 = xr[lane];
    float4 a1 = xr[lane + 64];
    float4 a2 = xr[lane + 128];
    float4 a3 = xr[lane + 192];
    float4 b0 = yr[lane];
    float4 b1 = yr[lane + 64];
    float4 b2 = yr[lane + 128];
    float4 b3 = yr[lane + 192];

    // split accumulators for ILP
    float s0 = a0.x * b0.x + a0.y * b0.y + a0.z * b0.z + a0.w * b0.w;
    float s1 = a1.x * b1.x + a1.y * b1.y + a1.z * b1.z + a1.w * b1.w;
    float s2 = a2.x * b2.x + a2.y * b2.y + a2.z * b2.z + a2.w * b2.w;
    float s3 = a3.x * b3.x + a3.y * b3.y + a3.z * b3.z + a3.w * b3.w;

    float v = (s0 + s1) + (s2 + s3);

    // wave-64 butterfly reduction
    #pragma unroll
    for (int off = 32; off > 0; off >>= 1) {
        v += __shfl_down(v, off, 64);
    }

    if (lane == 0) {
        out[row] = v;
    }
}

extern "C" void kernel_launch(void* const* d_in, const int* in_sizes, int n_in,
                              void* d_out, int out_size, void* d_ws, size_t ws_size,
                              hipStream_t stream) {
    const float* x = (const float*)d_in[0];
    const float* y = (const float*)d_in[1];
    float* out = (float*)d_out;
    const int N = out_size;  // 16384 rows

    rowdot_kernel<<<N / 4, 256, 0, stream>>>(x, y, out);
}